// Round 15
// baseline (189.931 us; speedup 1.0000x reference)
//
#include <hip/hip_runtime.h>

#define SEQ 2048
#define BATCH 2
#define HIDDEN 2048
#define NHEADS 16
#define NKV 4
#define HD 128
#define GROUP 768       // (4+2)*128
#define TPROJ 3072      // 4*768
#define NTOK (SEQ*BATCH)  // 4096

typedef __attribute__((ext_vector_type(8))) __bf16 bf16x8;
typedef __attribute__((ext_vector_type(8))) unsigned short ushort8_t;
typedef __attribute__((ext_vector_type(4))) float f32x4;

union U8cast { ushort8_t u; bf16x8 b; };
__device__ inline bf16x8 as_bf(ushort8_t u) { U8cast c; c.u = u; return c.b; }

union Bf16U { __bf16 h; unsigned short u; };

// fp32 -> bf16 round-to-nearest-even
__device__ inline unsigned short f2bf(float f) {
    unsigned int u = __float_as_uint(f);
    return (unsigned short)((u + 0x7FFFu + ((u >> 16) & 1u)) >> 16);
}

__device__ inline ushort8_t load8_f32_bf16(const float* __restrict__ p) {
    float4 v0 = *(const float4*)p;
    float4 v1 = *(const float4*)(p + 4);
    ushort8_t u;
    u[0] = f2bf(v0.x); u[1] = f2bf(v0.y); u[2] = f2bf(v0.z); u[3] = f2bf(v0.w);
    u[4] = f2bf(v1.x); u[5] = f2bf(v1.y); u[6] = f2bf(v1.z); u[7] = f2bf(v1.w);
    return u;
}

// native 2^x
__device__ inline float exp2a(float x) {
    float r; asm("v_exp_f32 %0, %1" : "=v"(r) : "v"(x)); return r;
}

// async global->LDS DMA, 16B per lane. LDS dest = wave-uniform base + lane*16.
__device__ inline void gload_lds16(const unsigned short* g, unsigned short* l) {
    __builtin_amdgcn_global_load_lds(
        (const __attribute__((address_space(1))) void*)g,
        (__attribute__((address_space(3))) void*)l, 16, 0, 0);
}

// fused fp32 -> bf16 convert of all three inputs (one launch)
#define CONV_N0 ((size_t)NTOK * HIDDEN)    // x:      8388608
#define CONV_N1 ((size_t)TPROJ * HIDDEN)   // wqkv:   6291456
#define CONV_N2 ((size_t)HIDDEN * HIDDEN)  // wproj:  4194304
__global__ __launch_bounds__(256) void conv3_kernel(
    const float* __restrict__ x, const float* __restrict__ wq, const float* __restrict__ wp,
    unsigned short* __restrict__ xb, unsigned short* __restrict__ wqb, unsigned short* __restrict__ wpb)
{
    size_t i = (size_t)(blockIdx.x * 256 + threadIdx.x) * 8;
    if (i < CONV_N0) {
        *(ushort8_t*)(xb + i) = load8_f32_bf16(x + i);
    } else if (i < CONV_N0 + CONV_N1) {
        size_t j = i - CONV_N0;
        *(ushort8_t*)(wqb + j) = load8_f32_bf16(wq + j);
    } else {
        size_t j = i - CONV_N0 - CONV_N1;
        *(ushort8_t*)(wpb + j) = load8_f32_bf16(wp + j);
    }
}

// ===========================================================================
// 256x256 coarse counted-vmcnt GEMM (R8/R9 config — session best). QKV proj.
// ===========================================================================
template<bool OUT_BF16>
__global__ __launch_bounds__(512, 2) void gemm256_kernel(
    const unsigned short* __restrict__ A, const unsigned short* __restrict__ B,
    void* __restrict__ Cv, int M, int N, int K)
{
    __shared__ unsigned short lds[2][2][256 * 64];   // [buf][0=A,1=B], 128 KiB

    const int t = threadIdx.x, lane = t & 63, w = t >> 6;
    const int wm = w >> 2, wn = w & 3;
    const int l16 = lane & 15, lg = lane >> 4;

    const int cpx = (int)gridDim.x >> 3;
    const int wg  = ((int)blockIdx.x & 7) * cpx + ((int)blockIdx.x >> 3);
    const int nbn = N >> 8;
    const int m0 = (wg / nbn) << 8, n0 = (wg % nbn) << 8;
    const int NKT = K >> 6;

    const int srow = lane >> 3;
    const int scol = ((lane & 7) ^ srow) << 3;

    f32x4 acc[8][4] = {};

    auto stage = [&](const unsigned short* __restrict__ G, int g0, int kt, int op) {
        const int k0 = kt << 6;
        unsigned short* Ld = lds[kt & 1][op];
#pragma unroll
        for (int i = 0; i < 4; ++i) {
            const int r = w * 32 + i * 8;
            gload_lds16(G + (size_t)(g0 + r + srow) * K + k0 + scol, Ld + r * 64);
        }
    };

    stage(A, m0, 0, 0); stage(B, n0, 0, 1);
    stage(A, m0, 1, 0); stage(B, n0, 1, 1);

    for (int kt = 0; kt < NKT; ++kt) {
        const unsigned short* As_ = lds[kt & 1][0];
        const unsigned short* Bs_ = lds[kt & 1][1];

        if (kt < NKT - 1) asm volatile("s_waitcnt vmcnt(8)" ::: "memory");
        else              asm volatile("s_waitcnt vmcnt(0)" ::: "memory");
        __builtin_amdgcn_sched_barrier(0);
        __builtin_amdgcn_s_barrier();
        __builtin_amdgcn_sched_barrier(0);

        bf16x8 aR[8], b0R[4], b1R[4];

#pragma unroll
        for (int i = 0; i < 4; ++i)
#pragma unroll
            for (int s = 0; s < 2; ++s) {
                int row  = wm * 128 + i * 16 + l16;
                int slot = ((s << 2) | lg) ^ (l16 & 7);
                aR[i * 2 + s] = as_bf(*(const ushort8_t*)&As_[row * 64 + slot * 8]);
            }
#pragma unroll
        for (int j = 0; j < 2; ++j)
#pragma unroll
            for (int s = 0; s < 2; ++s) {
                int row  = wn * 64 + j * 16 + l16;
                int slot = ((s << 2) | lg) ^ (l16 & 7);
                b0R[j * 2 + s] = as_bf(*(const ushort8_t*)&Bs_[row * 64 + slot * 8]);
            }
        __builtin_amdgcn_s_setprio(1);
#pragma unroll
        for (int i = 0; i < 4; ++i)
#pragma unroll
            for (int j = 0; j < 2; ++j)
#pragma unroll
                for (int s = 0; s < 2; ++s)
                    acc[i][j] = __builtin_amdgcn_mfma_f32_16x16x32_bf16(aR[i*2+s], b0R[j*2+s], acc[i][j], 0, 0, 0);
        __builtin_amdgcn_s_setprio(0);

#pragma unroll
        for (int j = 0; j < 2; ++j)
#pragma unroll
            for (int s = 0; s < 2; ++s) {
                int row  = wn * 64 + 32 + j * 16 + l16;
                int slot = ((s << 2) | lg) ^ (l16 & 7);
                b1R[j * 2 + s] = as_bf(*(const ushort8_t*)&Bs_[row * 64 + slot * 8]);
            }
        __builtin_amdgcn_s_setprio(1);
#pragma unroll
        for (int i = 0; i < 4; ++i)
#pragma unroll
            for (int j = 0; j < 2; ++j)
#pragma unroll
                for (int s = 0; s < 2; ++s)
                    acc[i][2 + j] = __builtin_amdgcn_mfma_f32_16x16x32_bf16(aR[i*2+s], b1R[j*2+s], acc[i][2 + j], 0, 0, 0);
        __builtin_amdgcn_s_setprio(0);

        __builtin_amdgcn_sched_barrier(0);
        __builtin_amdgcn_s_barrier();
        __builtin_amdgcn_sched_barrier(0);
        if (kt + 2 < NKT) stage(B, n0, kt + 2, 1);
        __builtin_amdgcn_sched_barrier(0);

#pragma unroll
        for (int i = 0; i < 4; ++i)
#pragma unroll
            for (int s = 0; s < 2; ++s) {
                int row  = wm * 128 + 64 + i * 16 + l16;
                int slot = ((s << 2) | lg) ^ (l16 & 7);
                aR[i * 2 + s] = as_bf(*(const ushort8_t*)&As_[row * 64 + slot * 8]);
            }
        __builtin_amdgcn_s_setprio(1);
#pragma unroll
        for (int i = 0; i < 4; ++i)
#pragma unroll
            for (int j = 0; j < 2; ++j)
#pragma unroll
                for (int s = 0; s < 2; ++s)
                    acc[4 + i][2 + j] = __builtin_amdgcn_mfma_f32_16x16x32_bf16(aR[i*2+s], b1R[j*2+s], acc[4 + i][2 + j], 0, 0, 0);
        __builtin_amdgcn_s_setprio(0);

        __builtin_amdgcn_sched_barrier(0);
        __builtin_amdgcn_s_barrier();
        __builtin_amdgcn_sched_barrier(0);
        if (kt + 2 < NKT) stage(A, m0, kt + 2, 0);
        __builtin_amdgcn_sched_barrier(0);

        __builtin_amdgcn_s_setprio(1);
#pragma unroll
        for (int i = 0; i < 4; ++i)
#pragma unroll
            for (int j = 0; j < 2; ++j)
#pragma unroll
                for (int s = 0; s < 2; ++s)
                    acc[4 + i][j] = __builtin_amdgcn_mfma_f32_16x16x32_bf16(aR[i*2+s], b0R[j*2+s], acc[4 + i][j], 0, 0, 0);
        __builtin_amdgcn_s_setprio(0);
    }

#pragma unroll
    for (int ia = 0; ia < 8; ++ia)
#pragma unroll
        for (int jb = 0; jb < 4; ++jb)
#pragma unroll
            for (int r = 0; r < 4; ++r) {
                int row = m0 + wm * 128 + (ia >> 2) * 64 + (ia & 3) * 16 + lg * 4 + r;
                int col = n0 + wn * 64 + (jb >> 1) * 32 + (jb & 1) * 16 + l16;
                if (OUT_BF16)
                    ((unsigned short*)Cv)[(size_t)row * N + col] = f2bf(acc[ia][jb][r]);
                else
                    ((float*)Cv)[(size_t)row * N + col] = acc[ia][jb][r];
            }
}

// ===========================================================================
// 256x128-tile GEMM (counted-vmcnt 4-phase; 256 blocks = full CU coverage for
// the output projection). R8/R9 config, unchanged.
// ===========================================================================
__global__ __launch_bounds__(512, 2) void gemm_tall_kernel(
    const unsigned short* __restrict__ A, const unsigned short* __restrict__ B,
    float* __restrict__ C, int M, int N, int K)
{
    __shared__ unsigned short ldsA[2][256 * 64];   // 64 KiB
    __shared__ unsigned short ldsB[2][128 * 64];   // 32 KiB

    const int t = threadIdx.x, lane = t & 63, w = t >> 6;
    const int wm = w >> 1, wn = w & 1;
    const int l16 = lane & 15, lg = lane >> 4;

    const int cpx = (int)gridDim.x >> 3;
    const int wg  = ((int)blockIdx.x & 7) * cpx + ((int)blockIdx.x >> 3);
    const int nbn = N >> 7;
    const int m0 = (wg / nbn) << 8, n0 = (wg % nbn) << 7;
    const int NKT = K >> 6;

    const int srow = lane >> 3;
    const int scol = ((lane & 7) ^ srow) << 3;

    f32x4 acc[4][4] = {};

    auto stageA = [&](int kt) {
        const int k0 = kt << 6;
        unsigned short* Ld = ldsA[kt & 1];
#pragma unroll
        for (int i = 0; i < 4; ++i) {
            const int r = w * 32 + i * 8;
            gload_lds16(A + (size_t)(m0 + r + srow) * K + k0 + scol, Ld + r * 64);
        }
    };
    auto stageB = [&](int kt) {
        const int k0 = kt << 6;
        unsigned short* Ld = ldsB[kt & 1];
#pragma unroll
        for (int i = 0; i < 2; ++i) {
            const int r = w * 16 + i * 8;
            gload_lds16(B + (size_t)(n0 + r + srow) * K + k0 + scol, Ld + r * 64);
        }
    };

    stageA(0); stageB(0);
    stageA(1); stageB(1);

    for (int kt = 0; kt < NKT; ++kt) {
        const unsigned short* As_ = ldsA[kt & 1];
        const unsigned short* Bs_ = ldsB[kt & 1];

        if (kt < NKT - 1) asm volatile("s_waitcnt vmcnt(6)" ::: "memory");
        else              asm volatile("s_waitcnt vmcnt(0)" ::: "memory");
        __builtin_amdgcn_sched_barrier(0);
        __builtin_amdgcn_s_barrier();
        __builtin_amdgcn_sched_barrier(0);

        bf16x8 aR[4], b0R[4], b1R[4];

#pragma unroll
        for (int i = 0; i < 2; ++i)
#pragma unroll
            for (int s = 0; s < 2; ++s) {
                int row  = wm * 64 + i * 16 + l16;
                int slot = ((s << 2) | lg) ^ (l16 & 7);
                aR[i * 2 + s] = as_bf(*(const ushort8_t*)&As_[row * 64 + slot * 8]);
            }
#pragma unroll
        for (int j = 0; j < 2; ++j)
#pragma unroll
            for (int s = 0; s < 2; ++s) {
                int row  = wn * 64 + j * 16 + l16;
                int slot = ((s << 2) | lg) ^ (l16 & 7);
                b0R[j * 2 + s] = as_bf(*(const ushort8_t*)&Bs_[row * 64 + slot * 8]);
            }
        __builtin_amdgcn_s_setprio(1);
#pragma unroll
        for (int i = 0; i < 2; ++i)
#pragma unroll
            for (int j = 0; j < 2; ++j)
#pragma unroll
                for (int s = 0; s < 2; ++s)
                    acc[i][j] = __builtin_amdgcn_mfma_f32_16x16x32_bf16(aR[i*2+s], b0R[j*2+s], acc[i][j], 0, 0, 0);
        __builtin_amdgcn_s_setprio(0);

#pragma unroll
        for (int j = 0; j < 2; ++j)
#pragma unroll
            for (int s = 0; s < 2; ++s) {
                int row  = wn * 64 + 32 + j * 16 + l16;
                int slot = ((s << 2) | lg) ^ (l16 & 7);
                b1R[j * 2 + s] = as_bf(*(const ushort8_t*)&Bs_[row * 64 + slot * 8]);
            }
        __builtin_amdgcn_s_setprio(1);
#pragma unroll
        for (int i = 0; i < 2; ++i)
#pragma unroll
            for (int j = 0; j < 2; ++j)
#pragma unroll
                for (int s = 0; s < 2; ++s)
                    acc[i][2 + j] = __builtin_amdgcn_mfma_f32_16x16x32_bf16(aR[i*2+s], b1R[j*2+s], acc[i][2 + j], 0, 0, 0);
        __builtin_amdgcn_s_setprio(0);

        __builtin_amdgcn_sched_barrier(0);
        __builtin_amdgcn_s_barrier();
        __builtin_amdgcn_sched_barrier(0);
        if (kt + 2 < NKT) stageB(kt + 2);
        __builtin_amdgcn_sched_barrier(0);

#pragma unroll
        for (int i = 0; i < 2; ++i)
#pragma unroll
            for (int s = 0; s < 2; ++s) {
                int row  = wm * 64 + 32 + i * 16 + l16;
                int slot = ((s << 2) | lg) ^ (l16 & 7);
                aR[i * 2 + s] = as_bf(*(const ushort8_t*)&As_[row * 64 + slot * 8]);
            }
        __builtin_amdgcn_s_setprio(1);
#pragma unroll
        for (int i = 0; i < 2; ++i)
#pragma unroll
            for (int j = 0; j < 2; ++j)
#pragma unroll
                for (int s = 0; s < 2; ++s)
                    acc[2 + i][2 + j] = __builtin_amdgcn_mfma_f32_16x16x32_bf16(aR[i*2+s], b1R[j*2+s], acc[2 + i][2 + j], 0, 0, 0);
        __builtin_amdgcn_s_setprio(0);

        __builtin_amdgcn_sched_barrier(0);
        __builtin_amdgcn_s_barrier();
        __builtin_amdgcn_sched_barrier(0);
        if (kt + 2 < NKT) stageA(kt + 2);
        __builtin_amdgcn_sched_barrier(0);

        __builtin_amdgcn_s_setprio(1);
#pragma unroll
        for (int i = 0; i < 2; ++i)
#pragma unroll
            for (int j = 0; j < 2; ++j)
#pragma unroll
                for (int s = 0; s < 2; ++s)
                    acc[2 + i][j] = __builtin_amdgcn_mfma_f32_16x16x32_bf16(aR[i*2+s], b0R[j*2+s], acc[2 + i][j], 0, 0, 0);
        __builtin_amdgcn_s_setprio(0);
    }

#pragma unroll
    for (int i = 0; i < 4; ++i)
#pragma unroll
        for (int j = 0; j < 4; ++j)
#pragma unroll
            for (int r = 0; r < 4; ++r) {
                int row = m0 + wm * 64 + i * 16 + lg * 4 + r;
                int col = n0 + wn * 64 + j * 16 + l16;
                C[(size_t)row * N + col] = acc[i][j][r];
            }
}

// V pre-transpose: vT[(bk*HD + d)*SEQ + s] = V[s,b,kvh][d], bk = b*NKV+kvh.
__global__ __launch_bounds__(256) void vtrans_kernel(const unsigned short* __restrict__ qkv,
                                                     unsigned short* __restrict__ vT)
{
    const int t = threadIdx.x;
    const int s0 = blockIdx.x * 128 + (t & 15) * 8;
    const int bk = blockIdx.y;
    const int b_idx = bk >> 2;
    const int voff = (bk & 3) * GROUP + 640;
    const int d0 = (t >> 4) * 8;
    ushort8_t in[8];
#pragma unroll
    for (int j = 0; j < 8; ++j)
        in[j] = *(const ushort8_t*)(qkv + (size_t)((s0 + j) * BATCH + b_idx) * TPROJ + voff + d0);
#pragma unroll
    for (int dd = 0; dd < 8; ++dd) {
        ushort8_t ov;
#pragma unroll
        for (int j = 0; j < 8; ++j) ov[j] = in[j][dd];
        *(ushort8_t*)(vT + (size_t)(bk * HD + d0 + dd) * SEQ + s0) = ov;
    }
}

// ===========================================================================
// Flash attention — ONE-BARRIER schedule: K AND V double-buffered (64 KB).
// Top of iter j: vmcnt(0) [tile j landed, issued a full iter ago] + barrier
// [all waves done reading tile j-1 -> buf[(j+1)&1] free] -> stage tile j+1
// -> QK/softmax/PV on buf[j&1]. No mid or bottom barrier (was 2/iter).
// Body identical to the R9 session-best (swapped QK^T, in-reg softmax,
// defer-max). 16 q-rows/wave, 4 waves, grid 1024 longest-first.
// ===========================================================================
__global__ __launch_bounds__(256, 2) void attn_kernel(const unsigned short* __restrict__ qkv,
                                                      const unsigned short* __restrict__ vT,
                                                      unsigned short* __restrict__ attn_out)
{
    __shared__ unsigned short Ks[2][64][128];        // K  [kv-logical][d], slot-swizzled
    __shared__ unsigned short Vt[2][128][64];        // V^T[d][kv], slot-swizzled

    const int t = threadIdx.x, lane = t & 63, w = t >> 6;
    const int l16 = lane & 15, lg = lane >> 4;

    // longest-first dispatch
    const int bid = (int)blockIdx.x;
    const int qt  = 127 - (bid >> 3);          // q-tile (16 rows)
    const int bk  = bid & 7;
    const int b_idx = bk >> 2;
    const int kvh   = bk & 3;
    const int qb0   = qt * 16;
    const int qoff  = kvh * GROUP + w * HD;    // this wave's q-head
    const int koff  = kvh * GROUP + 512;
    const int vrow0 = (b_idx * NKV + kvh) * HD;
    const int h     = kvh * 4 + w;

    const float SCL2 = 0.08838834764831845f * 1.44269504f;  // scale*log2(e)
    const float THRU = 8.0f / SCL2;                          // defer-max threshold

    // Q as B-operand fragments: row = l16 = q, k-chunk by lg
    ushort8_t qf[4];
    {
        size_t qrow = (size_t)((qb0 + l16) * BATCH + b_idx) * TPROJ + qoff;
#pragma unroll
        for (int kc = 0; kc < 4; ++kc)
            qf[kc] = *(const ushort8_t*)(qkv + qrow + kc * 32 + lg * 8);
    }

    f32x4 o[8] = {};                       // O: q = qb0 + 4*lg + r, d = 16f + l16
    float mstate = -1e30f, lstate = 0.f, negm2 = 0.f;   // per-lane, q = qb0 + l16

    const int nIter = (qt >> 2) + 1;       // KV tiles of 64 (causal)

    // DMA stage: pre-swizzled global source, linear LDS dest (rule #21).
    auto stageK = [&](int it) {
        const int kv0 = it << 6;
        const int buf = it & 1;
#pragma unroll
        for (int i = 0; i < 4; ++i) {
            int rl = w * 16 + i * 4 + (lane >> 4);          // lds logical row
            int pr = 32 * ((rl >> 4) & 1) + 8 * ((rl >> 2) & 3) + 4 * (rl >> 5) + (rl & 3);
            int g  = (lane & 15) ^ (rl & 7);                // source slot
            gload_lds16(qkv + (size_t)((kv0 + pr) * BATCH + b_idx) * TPROJ + koff + g * 8,
                        &Ks[buf][w * 16 + i * 4][0]);
        }
    };
    auto stageV = [&](int it) {
        const int kv0 = it << 6;
        const int buf = it & 1;
#pragma unroll
        for (int i = 0; i < 4; ++i) {
            int rl = w * 32 + i * 8 + (lane >> 3);
            int g  = (lane & 7) ^ ((lane >> 3) & 7);
            gload_lds16(vT + (size_t)(vrow0 + rl) * SEQ + kv0 + g * 8,
                        &Vt[buf][w * 32 + i * 8][0]);
        }
    };

    stageK(0); stageV(0);

    for (int it = 0; it < nIter; ++it) {
        const int kv0 = it * 64;
        const int buf = it & 1;

        asm volatile("s_waitcnt vmcnt(0)" ::: "memory");  // tile it landed (full-iter cover)
        __builtin_amdgcn_sched_barrier(0);
        __builtin_amdgcn_s_barrier();        // + all waves done reading tile it-1
        __builtin_amdgcn_sched_barrier(0);

        // stage tile it+1 into buf^1 (freed by the barrier above)
        if (it + 1 < nIter) { stageK(it + 1); stageV(it + 1); }
        __builtin_amdgcn_sched_barrier(0);

        // --- swapped QK^T: s[nf] = K_frag(nf) . Q^T -> D[kv-local][q=l16] ---
        f32x4 s[4] = {};
        __builtin_amdgcn_s_setprio(1);
#pragma unroll
        for (int nf = 0; nf < 4; ++nf)
#pragma unroll
            for (int kc = 0; kc < 4; ++kc) {
                int phys = (kc * 4 + lg) ^ (l16 & 7);
                ushort8_t kb = *(const ushort8_t*)&Ks[buf][nf * 16 + l16][phys * 8];
                s[nf] = __builtin_amdgcn_mfma_f32_16x16x32_bf16(as_bf(kb), as_bf(qf[kc]), s[nf], 0, 0, 0);
            }
        __builtin_amdgcn_s_setprio(0);

        // --- causal mask (final tile only); value (nf,r) is PHYSICAL kv:
        //     kv0 + 32*(nf&1) + 8*lg + 4*(nf>>1) + r ---
        if (it == nIter - 1) {
            const int q_g = qb0 + l16;
#pragma unroll
            for (int nf = 0; nf < 4; ++nf)
#pragma unroll
                for (int r = 0; r < 4; ++r) {
                    int kv_g = kv0 + 32 * (nf & 1) + 8 * lg + 4 * (nf >> 1) + r;
                    if (kv_g > q_g) s[nf][r] = -1e30f;
                }
        }

        // --- row max: in-lane tree + 2 shfl rounds over lane replicas ---
        float a0 = fmaxf(fmaxf(s[0][0], s[0][1]), fmaxf(s[0][2], s[0][3]));
        float a1 = fmaxf(fmaxf(s[1][0], s[1][1]), fmaxf(s[1][2], s[1][3]));
        float a2 = fmaxf(fmaxf(s[2][0], s[2][1]), fmaxf(s[2][2], s[2][3]));
        float a3 = fmaxf(fmaxf(s[3][0], s[3][1]), fmaxf(s[3][2], s[3][3]));
        float rmax = fmaxf(fmaxf(a0, a1), fmaxf(a2, a3));
        rmax = fmaxf(rmax, __shfl_xor(rmax, 16));
        rmax = fmaxf(rmax, __shfl_xor(rmax, 32));

        // --- defer-max: rescale only when max grew beyond threshold ---
        if (!__all(rmax - mstate <= THRU)) {
            float mn = fmaxf(mstate, rmax);
            float corr = exp2a((mstate - mn) * SCL2);
            mstate = mn;
            negm2  = -mn * SCL2;
            lstate *= corr;
            float co[4];
#pragma unroll
            for (int r = 0; r < 4; ++r) co[r] = __shfl(corr, 4 * lg + r);
#pragma unroll
            for (int f = 0; f < 8; ++f)
#pragma unroll
                for (int r = 0; r < 4; ++r) o[f][r] *= co[r];
        }

        // --- P = exp2(s*SCL2 - m*SCL2) in place; in-lane row sum ---
        float rs0 = 0.f, rs1 = 0.f;
#pragma unroll
        for (int nf = 0; nf < 4; ++nf)
#pragma unroll
            for (int r = 0; r < 4; ++r) {
                float pv = exp2a(fmaf(s[nf][r], SCL2, negm2));
                s[nf][r] = pv;
                if (nf < 2) rs0 += pv; else rs1 += pv;
            }
        float rsum = rs0 + rs1;
        rsum += __shfl_xor(rsum, 16);
        rsum += __shfl_xor(rsum, 32);
        lstate += rsum;

        // paf[c]: elems 0..3 = p[c][0..3], elems 4..7 = p[2+c][0..3]
        ushort8_t paf[2];
#pragma unroll
        for (int c = 0; c < 2; ++c)
#pragma unroll
            for (int e = 0; e < 8; ++e) {
                Bf16U cv; cv.h = (__bf16)((e < 4) ? s[c][e] : s[2 + c][e - 4]);
                paf[c][e] = cv.u;
            }

        // --- PV: O[16 q][128 d] += P[16][64] @ V[64][128] ---
        __builtin_amdgcn_s_setprio(1);
#pragma unroll
        for (int c = 0; c < 2; ++c)
#pragma unroll
            for (int f = 0; f < 8; ++f) {
                int phys = (c * 4 + lg) ^ (l16 & 7);
                ushort8_t vf = *(const ushort8_t*)&Vt[buf][l16 + 16 * f][phys * 8];
                o[f] = __builtin_amdgcn_mfma_f32_16x16x32_bf16(as_bf(paf[c]), as_bf(vf), o[f], 0, 0, 0);
            }
        __builtin_amdgcn_s_setprio(0);
        // no further barrier: next top barrier certifies these reads retired
    }

    // --- epilogue: normalize (redistribute 1/lstate to o's q-rows) and store ---
    float li = 1.0f / lstate;
    float linv[4];
#pragma unroll
    for (int r = 0; r < 4; ++r) linv[r] = __shfl(li, 4 * lg + r);
#pragma unroll
    for (int f = 0; f < 8; ++f)
#pragma unroll
        for (int r = 0; r < 4; ++r) {
            int q_g = qb0 + lg * 4 + r;
            size_t row = (size_t)(q_g * BATCH + b_idx) * HIDDEN;
            attn_out[row + h * HD + 16 * f + l16] = f2bf(o[f][r] * linv[r]);
        }
}

extern "C" void kernel_launch(void* const* d_in, const int* in_sizes, int n_in,
                              void* d_out, int out_size, void* d_ws, size_t ws_size,
                              hipStream_t stream) {
    const float* x     = (const float*)d_in[0];
    const float* wqkv  = (const float*)d_in[1];
    const float* wproj = (const float*)d_in[2];
    float* out = (float*)d_out;

    unsigned short* qkv   = (unsigned short*)d_ws;                    // [NTOK][TPROJ]
    unsigned short* attn  = qkv  + (size_t)NTOK * TPROJ;              // [NTOK][HIDDEN]
    unsigned short* vT    = attn + (size_t)NTOK * HIDDEN;             // [B*NKV*HD][SEQ]
    unsigned short* xb    = vT   + (size_t)BATCH * NKV * HD * SEQ;    // [NTOK][HIDDEN]
    unsigned short* wqkvb = xb   + (size_t)NTOK * HIDDEN;             // [TPROJ][HIDDEN]
    unsigned short* wprojb= wqkvb+ (size_t)TPROJ * HIDDEN;            // [HIDDEN][HIDDEN]

    // 0) fused bf16 pre-convert
    conv3_kernel<<<dim3((unsigned)((CONV_N0 + CONV_N1 + CONV_N2) / 2048)), 256, 0, stream>>>(
        x, wqkv, wproj, xb, wqkvb, wprojb);

    // 1) QKV projection: qkv = x @ wqkv^T  (bf16 in, bf16 out). 192 blocks
    gemm256_kernel<true><<<dim3((NTOK / 256) * (TPROJ / 256)), 512, 0, stream>>>(
        xb, wqkvb, (void*)qkv, NTOK, TPROJ, HIDDEN);

    // 2) V pre-transpose
    vtrans_kernel<<<dim3(SEQ / 128, BATCH * NKV), 256, 0, stream>>>(qkv, vT);

    // 3) causal GQA flash attention (1024 blocks, longest-first, 1-barrier loop)
    attn_kernel<<<dim3(1024), 256, 0, stream>>>(qkv, vT, attn);

    // 4) output projection: 256x128 tile -> 256 blocks = full CU coverage
    gemm_tall_kernel<<<dim3((NTOK / 256) * (HIDDEN / 128)), 512, 0, stream>>>(
        attn, wprojb, out, NTOK, HIDDEN, HIDDEN);
}

// Round 16
// 181.747 us; speedup vs baseline: 1.0450x; 1.0450x over previous
//
#include <hip/hip_runtime.h>

#define SEQ 2048
#define BATCH 2
#define HIDDEN 2048
#define NHEADS 16
#define NKV 4
#define HD 128
#define GROUP 768       // (4+2)*128
#define TPROJ 3072      // 4*768
#define NTOK (SEQ*BATCH)  // 4096

typedef __attribute__((ext_vector_type(8))) __bf16 bf16x8;
typedef __attribute__((ext_vector_type(8))) unsigned short ushort8_t;
typedef __attribute__((ext_vector_type(4))) float f32x4;

union U8cast { ushort8_t u; bf16x8 b; };
__device__ inline bf16x8 as_bf(ushort8_t u) { U8cast c; c.u = u; return c.b; }

union Bf16U { __bf16 h; unsigned short u; };

// fp32 -> bf16 round-to-nearest-even
__device__ inline unsigned short f2bf(float f) {
    unsigned int u = __float_as_uint(f);
    return (unsigned short)((u + 0x7FFFu + ((u >> 16) & 1u)) >> 16);
}

__device__ inline ushort8_t load8_f32_bf16(const float* __restrict__ p) {
    float4 v0 = *(const float4*)p;
    float4 v1 = *(const float4*)(p + 4);
    ushort8_t u;
    u[0] = f2bf(v0.x); u[1] = f2bf(v0.y); u[2] = f2bf(v0.z); u[3] = f2bf(v0.w);
    u[4] = f2bf(v1.x); u[5] = f2bf(v1.y); u[6] = f2bf(v1.z); u[7] = f2bf(v1.w);
    return u;
}

// native 2^x
__device__ inline float exp2a(float x) {
    float r; asm("v_exp_f32 %0, %1" : "=v"(r) : "v"(x)); return r;
}

// async global->LDS DMA, 16B per lane. LDS dest = wave-uniform base + lane*16.
__device__ inline void gload_lds16(const unsigned short* g, unsigned short* l) {
    __builtin_amdgcn_global_load_lds(
        (const __attribute__((address_space(1))) void*)g,
        (__attribute__((address_space(3))) void*)l, 16, 0, 0);
}

// fused fp32 -> bf16 convert of all three inputs (one launch)
#define CONV_N0 ((size_t)NTOK * HIDDEN)    // x:      8388608
#define CONV_N1 ((size_t)TPROJ * HIDDEN)   // wqkv:   6291456
#define CONV_N2 ((size_t)HIDDEN * HIDDEN)  // wproj:  4194304
__global__ __launch_bounds__(256) void conv3_kernel(
    const float* __restrict__ x, const float* __restrict__ wq, const float* __restrict__ wp,
    unsigned short* __restrict__ xb, unsigned short* __restrict__ wqb, unsigned short* __restrict__ wpb)
{
    size_t i = (size_t)(blockIdx.x * 256 + threadIdx.x) * 8;
    if (i < CONV_N0) {
        *(ushort8_t*)(xb + i) = load8_f32_bf16(x + i);
    } else if (i < CONV_N0 + CONV_N1) {
        size_t j = i - CONV_N0;
        *(ushort8_t*)(wqb + j) = load8_f32_bf16(wq + j);
    } else {
        size_t j = i - CONV_N0 - CONV_N1;
        *(ushort8_t*)(wpb + j) = load8_f32_bf16(wp + j);
    }
}

// ===========================================================================
// 256x256 coarse counted-vmcnt GEMM (R8/R9 config — session best). QKV proj.
// ===========================================================================
template<bool OUT_BF16>
__global__ __launch_bounds__(512, 2) void gemm256_kernel(
    const unsigned short* __restrict__ A, const unsigned short* __restrict__ B,
    void* __restrict__ Cv, int M, int N, int K)
{
    __shared__ unsigned short lds[2][2][256 * 64];   // [buf][0=A,1=B], 128 KiB

    const int t = threadIdx.x, lane = t & 63, w = t >> 6;
    const int wm = w >> 2, wn = w & 3;
    const int l16 = lane & 15, lg = lane >> 4;

    const int cpx = (int)gridDim.x >> 3;
    const int wg  = ((int)blockIdx.x & 7) * cpx + ((int)blockIdx.x >> 3);
    const int nbn = N >> 8;
    const int m0 = (wg / nbn) << 8, n0 = (wg % nbn) << 8;
    const int NKT = K >> 6;

    const int srow = lane >> 3;
    const int scol = ((lane & 7) ^ srow) << 3;

    f32x4 acc[8][4] = {};

    auto stage = [&](const unsigned short* __restrict__ G, int g0, int kt, int op) {
        const int k0 = kt << 6;
        unsigned short* Ld = lds[kt & 1][op];
#pragma unroll
        for (int i = 0; i < 4; ++i) {
            const int r = w * 32 + i * 8;
            gload_lds16(G + (size_t)(g0 + r + srow) * K + k0 + scol, Ld + r * 64);
        }
    };

    stage(A, m0, 0, 0); stage(B, n0, 0, 1);
    stage(A, m0, 1, 0); stage(B, n0, 1, 1);

    for (int kt = 0; kt < NKT; ++kt) {
        const unsigned short* As_ = lds[kt & 1][0];
        const unsigned short* Bs_ = lds[kt & 1][1];

        if (kt < NKT - 1) asm volatile("s_waitcnt vmcnt(8)" ::: "memory");
        else              asm volatile("s_waitcnt vmcnt(0)" ::: "memory");
        __builtin_amdgcn_sched_barrier(0);
        __builtin_amdgcn_s_barrier();
        __builtin_amdgcn_sched_barrier(0);

        bf16x8 aR[8], b0R[4], b1R[4];

#pragma unroll
        for (int i = 0; i < 4; ++i)
#pragma unroll
            for (int s = 0; s < 2; ++s) {
                int row  = wm * 128 + i * 16 + l16;
                int slot = ((s << 2) | lg) ^ (l16 & 7);
                aR[i * 2 + s] = as_bf(*(const ushort8_t*)&As_[row * 64 + slot * 8]);
            }
#pragma unroll
        for (int j = 0; j < 2; ++j)
#pragma unroll
            for (int s = 0; s < 2; ++s) {
                int row  = wn * 64 + j * 16 + l16;
                int slot = ((s << 2) | lg) ^ (l16 & 7);
                b0R[j * 2 + s] = as_bf(*(const ushort8_t*)&Bs_[row * 64 + slot * 8]);
            }
        __builtin_amdgcn_s_setprio(1);
#pragma unroll
        for (int i = 0; i < 4; ++i)
#pragma unroll
            for (int j = 0; j < 2; ++j)
#pragma unroll
                for (int s = 0; s < 2; ++s)
                    acc[i][j] = __builtin_amdgcn_mfma_f32_16x16x32_bf16(aR[i*2+s], b0R[j*2+s], acc[i][j], 0, 0, 0);
        __builtin_amdgcn_s_setprio(0);

#pragma unroll
        for (int j = 0; j < 2; ++j)
#pragma unroll
            for (int s = 0; s < 2; ++s) {
                int row  = wn * 64 + 32 + j * 16 + l16;
                int slot = ((s << 2) | lg) ^ (l16 & 7);
                b1R[j * 2 + s] = as_bf(*(const ushort8_t*)&Bs_[row * 64 + slot * 8]);
            }
        __builtin_amdgcn_s_setprio(1);
#pragma unroll
        for (int i = 0; i < 4; ++i)
#pragma unroll
            for (int j = 0; j < 2; ++j)
#pragma unroll
                for (int s = 0; s < 2; ++s)
                    acc[i][2 + j] = __builtin_amdgcn_mfma_f32_16x16x32_bf16(aR[i*2+s], b1R[j*2+s], acc[i][2 + j], 0, 0, 0);
        __builtin_amdgcn_s_setprio(0);

        __builtin_amdgcn_sched_barrier(0);
        __builtin_amdgcn_s_barrier();
        __builtin_amdgcn_sched_barrier(0);
        if (kt + 2 < NKT) stage(B, n0, kt + 2, 1);
        __builtin_amdgcn_sched_barrier(0);

#pragma unroll
        for (int i = 0; i < 4; ++i)
#pragma unroll
            for (int s = 0; s < 2; ++s) {
                int row  = wm * 128 + 64 + i * 16 + l16;
                int slot = ((s << 2) | lg) ^ (l16 & 7);
                aR[i * 2 + s] = as_bf(*(const ushort8_t*)&As_[row * 64 + slot * 8]);
            }
        __builtin_amdgcn_s_setprio(1);
#pragma unroll
        for (int i = 0; i < 4; ++i)
#pragma unroll
            for (int j = 0; j < 2; ++j)
#pragma unroll
                for (int s = 0; s < 2; ++s)
                    acc[4 + i][2 + j] = __builtin_amdgcn_mfma_f32_16x16x32_bf16(aR[i*2+s], b1R[j*2+s], acc[4 + i][2 + j], 0, 0, 0);
        __builtin_amdgcn_s_setprio(0);

        __builtin_amdgcn_sched_barrier(0);
        __builtin_amdgcn_s_barrier();
        __builtin_amdgcn_sched_barrier(0);
        if (kt + 2 < NKT) stage(A, m0, kt + 2, 0);
        __builtin_amdgcn_sched_barrier(0);

        __builtin_amdgcn_s_setprio(1);
#pragma unroll
        for (int i = 0; i < 4; ++i)
#pragma unroll
            for (int j = 0; j < 2; ++j)
#pragma unroll
                for (int s = 0; s < 2; ++s)
                    acc[4 + i][j] = __builtin_amdgcn_mfma_f32_16x16x32_bf16(aR[i*2+s], b0R[j*2+s], acc[4 + i][j], 0, 0, 0);
        __builtin_amdgcn_s_setprio(0);
    }

#pragma unroll
    for (int ia = 0; ia < 8; ++ia)
#pragma unroll
        for (int jb = 0; jb < 4; ++jb)
#pragma unroll
            for (int r = 0; r < 4; ++r) {
                int row = m0 + wm * 128 + (ia >> 2) * 64 + (ia & 3) * 16 + lg * 4 + r;
                int col = n0 + wn * 64 + (jb >> 1) * 32 + (jb & 1) * 16 + l16;
                if (OUT_BF16)
                    ((unsigned short*)Cv)[(size_t)row * N + col] = f2bf(acc[ia][jb][r]);
                else
                    ((float*)Cv)[(size_t)row * N + col] = acc[ia][jb][r];
            }
}

// ===========================================================================
// Output projection GEMM: 128x128 tile, 256 thr (4 waves 2Mx2N, per-wave
// 64x64), BK=64, dbuf LDS = 64 KB -> 2 BLOCKS/CU (grid 512 = 2x per CU).
// Mechanism: two independent barrier domains per CU; one block's vmcnt/
// barrier stalls hide under the other's MFMA. Same coarse counted-vmcnt
// 4-phase schedule as the proven gemm_tall (8 issues/tile/wave -> vmcnt(8)).
// ===========================================================================
__global__ __launch_bounds__(256, 2) void gemm_proj_kernel(
    const unsigned short* __restrict__ A, const unsigned short* __restrict__ B,
    float* __restrict__ C, int M, int N, int K)
{
    __shared__ unsigned short ldsA[2][128 * 64];   // 32 KiB
    __shared__ unsigned short ldsB[2][128 * 64];   // 32 KiB

    const int t = threadIdx.x, lane = t & 63, w = t >> 6;
    const int wm = w >> 1, wn = w & 1;
    const int l16 = lane & 15, lg = lane >> 4;

    const int cpx = (int)gridDim.x >> 3;
    const int wg  = ((int)blockIdx.x & 7) * cpx + ((int)blockIdx.x >> 3);
    const int nbn = N >> 7;
    const int m0 = (wg / nbn) << 7, n0 = (wg % nbn) << 7;
    const int NKT = K >> 6;

    const int srow = lane >> 3;
    const int scol = ((lane & 7) ^ srow) << 3;

    f32x4 acc[4][4] = {};

    auto stageA = [&](int kt) {                    // 4 issues/wave: rows w*32..+31
        const int k0 = kt << 6;
        unsigned short* Ld = ldsA[kt & 1];
#pragma unroll
        for (int i = 0; i < 4; ++i) {
            const int r = w * 32 + i * 8;
            gload_lds16(A + (size_t)(m0 + r + srow) * K + k0 + scol, Ld + r * 64);
        }
    };
    auto stageB = [&](int kt) {                    // 4 issues/wave
        const int k0 = kt << 6;
        unsigned short* Ld = ldsB[kt & 1];
#pragma unroll
        for (int i = 0; i < 4; ++i) {
            const int r = w * 32 + i * 8;
            gload_lds16(B + (size_t)(n0 + r + srow) * K + k0 + scol, Ld + r * 64);
        }
    };

    stageA(0); stageB(0);
    stageA(1); stageB(1);

    for (int kt = 0; kt < NKT; ++kt) {
        const unsigned short* As_ = ldsA[kt & 1];
        const unsigned short* Bs_ = ldsB[kt & 1];

        if (kt < NKT - 1) asm volatile("s_waitcnt vmcnt(8)" ::: "memory");
        else              asm volatile("s_waitcnt vmcnt(0)" ::: "memory");
        __builtin_amdgcn_sched_barrier(0);
        __builtin_amdgcn_s_barrier();
        __builtin_amdgcn_sched_barrier(0);

        bf16x8 aR[4], b0R[4], b1R[4];

        // P1: a0 (rows wm*64 + {0,16}) + b0 (cols wn*64 + {0,16}) -> 8 MFMA
#pragma unroll
        for (int i = 0; i < 2; ++i)
#pragma unroll
            for (int s = 0; s < 2; ++s) {
                int row  = wm * 64 + i * 16 + l16;
                int slot = ((s << 2) | lg) ^ (l16 & 7);
                aR[i * 2 + s] = as_bf(*(const ushort8_t*)&As_[row * 64 + slot * 8]);
            }
#pragma unroll
        for (int j = 0; j < 2; ++j)
#pragma unroll
            for (int s = 0; s < 2; ++s) {
                int row  = wn * 64 + j * 16 + l16;
                int slot = ((s << 2) | lg) ^ (l16 & 7);
                b0R[j * 2 + s] = as_bf(*(const ushort8_t*)&Bs_[row * 64 + slot * 8]);
            }
        __builtin_amdgcn_s_setprio(1);
#pragma unroll
        for (int i = 0; i < 2; ++i)
#pragma unroll
            for (int j = 0; j < 2; ++j)
#pragma unroll
                for (int s = 0; s < 2; ++s)
                    acc[i][j] = __builtin_amdgcn_mfma_f32_16x16x32_bf16(aR[i*2+s], b0R[j*2+s], acc[i][j], 0, 0, 0);
        __builtin_amdgcn_s_setprio(0);

        // P2: b1 (cols wn*64 + {32,48}) -> 8 MFMA
#pragma unroll
        for (int j = 0; j < 2; ++j)
#pragma unroll
            for (int s = 0; s < 2; ++s) {
                int row  = wn * 64 + 32 + j * 16 + l16;
                int slot = ((s << 2) | lg) ^ (l16 & 7);
                b1R[j * 2 + s] = as_bf(*(const ushort8_t*)&Bs_[row * 64 + slot * 8]);
            }
        __builtin_amdgcn_s_setprio(1);
#pragma unroll
        for (int i = 0; i < 2; ++i)
#pragma unroll
            for (int j = 0; j < 2; ++j)
#pragma unroll
                for (int s = 0; s < 2; ++s)
                    acc[i][2 + j] = __builtin_amdgcn_mfma_f32_16x16x32_bf16(aR[i*2+s], b1R[j*2+s], acc[i][2 + j], 0, 0, 0);
        __builtin_amdgcn_s_setprio(0);

        // B region fully in registers -> barrier, stage B(kt+2)
        __builtin_amdgcn_sched_barrier(0);
        __builtin_amdgcn_s_barrier();
        __builtin_amdgcn_sched_barrier(0);
        if (kt + 2 < NKT) stageB(kt + 2);
        __builtin_amdgcn_sched_barrier(0);

        // P3: a1 (rows wm*64 + {32,48}) -> 8 MFMA vs b1
#pragma unroll
        for (int i = 0; i < 2; ++i)
#pragma unroll
            for (int s = 0; s < 2; ++s) {
                int row  = wm * 64 + 32 + i * 16 + l16;
                int slot = ((s << 2) | lg) ^ (l16 & 7);
                aR[i * 2 + s] = as_bf(*(const ushort8_t*)&As_[row * 64 + slot * 8]);
            }
        __builtin_amdgcn_s_setprio(1);
#pragma unroll
        for (int i = 0; i < 2; ++i)
#pragma unroll
            for (int j = 0; j < 2; ++j)
#pragma unroll
                for (int s = 0; s < 2; ++s)
                    acc[2 + i][2 + j] = __builtin_amdgcn_mfma_f32_16x16x32_bf16(aR[i*2+s], b1R[j*2+s], acc[2 + i][2 + j], 0, 0, 0);
        __builtin_amdgcn_s_setprio(0);

        // A region fully in registers -> barrier, stage A(kt+2)
        __builtin_amdgcn_sched_barrier(0);
        __builtin_amdgcn_s_barrier();
        __builtin_amdgcn_sched_barrier(0);
        if (kt + 2 < NKT) stageA(kt + 2);
        __builtin_amdgcn_sched_barrier(0);

        // P4: a1 x b0 -> 8 MFMA (register-only)
        __builtin_amdgcn_s_setprio(1);
#pragma unroll
        for (int i = 0; i < 2; ++i)
#pragma unroll
            for (int j = 0; j < 2; ++j)
#pragma unroll
                for (int s = 0; s < 2; ++s)
                    acc[2 + i][j] = __builtin_amdgcn_mfma_f32_16x16x32_bf16(aR[i*2+s], b0R[j*2+s], acc[2 + i][j], 0, 0, 0);
        __builtin_amdgcn_s_setprio(0);
    }

#pragma unroll
    for (int i = 0; i < 4; ++i)
#pragma unroll
        for (int j = 0; j < 4; ++j)
#pragma unroll
            for (int r = 0; r < 4; ++r) {
                int row = m0 + wm * 64 + i * 16 + lg * 4 + r;
                int col = n0 + wn * 64 + j * 16 + l16;
                C[(size_t)row * N + col] = acc[i][j][r];
            }
}

// V pre-transpose: vT[(bk*HD + d)*SEQ + s] = V[s,b,kvh][d], bk = b*NKV+kvh.
__global__ __launch_bounds__(256) void vtrans_kernel(const unsigned short* __restrict__ qkv,
                                                     unsigned short* __restrict__ vT)
{
    const int t = threadIdx.x;
    const int s0 = blockIdx.x * 128 + (t & 15) * 8;
    const int bk = blockIdx.y;
    const int b_idx = bk >> 2;
    const int voff = (bk & 3) * GROUP + 640;
    const int d0 = (t >> 4) * 8;
    ushort8_t in[8];
#pragma unroll
    for (int j = 0; j < 8; ++j)
        in[j] = *(const ushort8_t*)(qkv + (size_t)((s0 + j) * BATCH + b_idx) * TPROJ + voff + d0);
#pragma unroll
    for (int dd = 0; dd < 8; ++dd) {
        ushort8_t ov;
#pragma unroll
        for (int j = 0; j < 8; ++j) ov[j] = in[j][dd];
        *(ushort8_t*)(vT + (size_t)(bk * HD + d0 + dd) * SEQ + s0) = ov;
    }
}

// ===========================================================================
// Flash attention (EXACT R9 session-best config, measured 67.0 us): swapped
// QK^T + kv-permuted K; K single-buf + V double-buf (48 KB -> 3 blocks/CU).
// Every DMA has a full compute phase of cover. 16 q-rows/wave, 4 waves,
// grid 1024 longest-first. FROZEN — five structural variants all neutral.
// ===========================================================================
__global__ __launch_bounds__(256, 4) void attn_kernel(const unsigned short* __restrict__ qkv,
                                                      const unsigned short* __restrict__ vT,
                                                      unsigned short* __restrict__ attn_out)
{
    __shared__ unsigned short Ks[64][128];           // K  [kv-logical][d], slot-swizzled
    __shared__ unsigned short Vt[2][128][64];        // V^T[d][kv], slot-swizzled, dbuf

    const int t = threadIdx.x, lane = t & 63, w = t >> 6;
    const int l16 = lane & 15, lg = lane >> 4;

    // longest-first dispatch
    const int bid = (int)blockIdx.x;
    const int qt  = 127 - (bid >> 3);          // q-tile (16 rows)
    const int bk  = bid & 7;
    const int b_idx = bk >> 2;
    const int kvh   = bk & 3;
    const int qb0   = qt * 16;
    const int qoff  = kvh * GROUP + w * HD;    // this wave's q-head
    const int koff  = kvh * GROUP + 512;
    const int vrow0 = (b_idx * NKV + kvh) * HD;
    const int h     = kvh * 4 + w;

    const float SCL2 = 0.08838834764831845f * 1.44269504f;  // scale*log2(e)
    const float THRU = 8.0f / SCL2;                          // defer-max threshold

    // Q as B-operand fragments: row = l16 = q, k-chunk by lg
    ushort8_t qf[4];
    {
        size_t qrow = (size_t)((qb0 + l16) * BATCH + b_idx) * TPROJ + qoff;
#pragma unroll
        for (int kc = 0; kc < 4; ++kc)
            qf[kc] = *(const ushort8_t*)(qkv + qrow + kc * 32 + lg * 8);
    }

    f32x4 o[8] = {};                       // O: q = qb0 + 4*lg + r, d = 16f + l16
    float mstate = -1e30f, lstate = 0.f, negm2 = 0.f;   // per-lane, q = qb0 + l16

    const int nIter = (qt >> 2) + 1;       // KV tiles of 64 (causal)

    // DMA stage: pre-swizzled global source, linear LDS dest (rule #21).
    auto stageK = [&](int it) {
        const int kv0 = it << 6;
#pragma unroll
        for (int i = 0; i < 4; ++i) {
            int rl = w * 16 + i * 4 + (lane >> 4);          // lds logical row
            int pr = 32 * ((rl >> 4) & 1) + 8 * ((rl >> 2) & 3) + 4 * (rl >> 5) + (rl & 3);
            int g  = (lane & 15) ^ (rl & 7);                // source slot
            gload_lds16(qkv + (size_t)((kv0 + pr) * BATCH + b_idx) * TPROJ + koff + g * 8,
                        &Ks[w * 16 + i * 4][0]);
        }
    };
    auto stageV = [&](int it) {
        const int kv0 = it << 6;
        const int buf = it & 1;
#pragma unroll
        for (int i = 0; i < 4; ++i) {
            int rl = w * 32 + i * 8 + (lane >> 3);
            int g  = (lane & 7) ^ ((lane >> 3) & 7);
            gload_lds16(vT + (size_t)(vrow0 + rl) * SEQ + kv0 + g * 8,
                        &Vt[buf][w * 32 + i * 8][0]);
        }
    };

    stageK(0); stageV(0);

    for (int it = 0; it < nIter; ++it) {
        const int kv0 = it * 64;
        const int vbuf = it & 1;

        asm volatile("s_waitcnt vmcnt(0)" ::: "memory");  // all covered >= a phase ago
        __builtin_amdgcn_sched_barrier(0);
        __builtin_amdgcn_s_barrier();        // tile it visible to all waves
        __builtin_amdgcn_sched_barrier(0);

        // V(it+1) into the other buffer (its readers retired before the barrier)
        if (it + 1 < nIter) stageV(it + 1);
        __builtin_amdgcn_sched_barrier(0);

        // --- swapped QK^T: s[nf] = K_frag(nf) . Q^T -> D[kv-local][q=l16] ---
        f32x4 s[4] = {};
        __builtin_amdgcn_s_setprio(1);
#pragma unroll
        for (int nf = 0; nf < 4; ++nf)
#pragma unroll
            for (int kc = 0; kc < 4; ++kc) {
                int phys = (kc * 4 + lg) ^ (l16 & 7);
                ushort8_t kb = *(const ushort8_t*)&Ks[nf * 16 + l16][phys * 8];
                s[nf] = __builtin_amdgcn_mfma_f32_16x16x32_bf16(as_bf(kb), as_bf(qf[kc]), s[nf], 0, 0, 0);
            }
        __builtin_amdgcn_s_setprio(0);

        // K reads retired -> barrier, then restage K (hides under softmax+PV)
        __builtin_amdgcn_sched_barrier(0);
        __builtin_amdgcn_s_barrier();
        __builtin_amdgcn_sched_barrier(0);
        if (it + 1 < nIter) stageK(it + 1);
        __builtin_amdgcn_sched_barrier(0);

        // --- causal mask (final tile only); value (nf,r) is PHYSICAL kv:
        //     kv0 + 32*(nf&1) + 8*lg + 4*(nf>>1) + r ---
        if (it == nIter - 1) {
            const int q_g = qb0 + l16;
#pragma unroll
            for (int nf = 0; nf < 4; ++nf)
#pragma unroll
                for (int r = 0; r < 4; ++r) {
                    int kv_g = kv0 + 32 * (nf & 1) + 8 * lg + 4 * (nf >> 1) + r;
                    if (kv_g > q_g) s[nf][r] = -1e30f;
                }
        }

        // --- row max: in-lane tree + 2 shfl rounds over lane replicas ---
        float a0 = fmaxf(fmaxf(s[0][0], s[0][1]), fmaxf(s[0][2], s[0][3]));
        float a1 = fmaxf(fmaxf(s[1][0], s[1][1]), fmaxf(s[1][2], s[1][3]));
        float a2 = fmaxf(fmaxf(s[2][0], s[2][1]), fmaxf(s[2][2], s[2][3]));
        float a3 = fmaxf(fmaxf(s[3][0], s[3][1]), fmaxf(s[3][2], s[3][3]));
        float rmax = fmaxf(fmaxf(a0, a1), fmaxf(a2, a3));
        rmax = fmaxf(rmax, __shfl_xor(rmax, 16));
        rmax = fmaxf(rmax, __shfl_xor(rmax, 32));

        // --- defer-max: rescale only when max grew beyond threshold ---
        if (!__all(rmax - mstate <= THRU)) {
            float mn = fmaxf(mstate, rmax);
            float corr = exp2a((mstate - mn) * SCL2);
            mstate = mn;
            negm2  = -mn * SCL2;
            lstate *= corr;
            float co[4];
#pragma unroll
            for (int r = 0; r < 4; ++r) co[r] = __shfl(corr, 4 * lg + r);
#pragma unroll
            for (int f = 0; f < 8; ++f)
#pragma unroll
                for (int r = 0; r < 4; ++r) o[f][r] *= co[r];
        }

        // --- P = exp2(s*SCL2 - m*SCL2) in place; in-lane row sum ---
        float rs0 = 0.f, rs1 = 0.f;
#pragma unroll
        for (int nf = 0; nf < 4; ++nf)
#pragma unroll
            for (int r = 0; r < 4; ++r) {
                float pv = exp2a(fmaf(s[nf][r], SCL2, negm2));
                s[nf][r] = pv;
                if (nf < 2) rs0 += pv; else rs1 += pv;
            }
        float rsum = rs0 + rs1;
        rsum += __shfl_xor(rsum, 16);
        rsum += __shfl_xor(rsum, 32);
        lstate += rsum;

        // paf[c]: elems 0..3 = p[c][0..3], elems 4..7 = p[2+c][0..3]
        ushort8_t paf[2];
#pragma unroll
        for (int c = 0; c < 2; ++c)
#pragma unroll
            for (int e = 0; e < 8; ++e) {
                Bf16U cv; cv.h = (__bf16)((e < 4) ? s[c][e] : s[2 + c][e - 4]);
                paf[c][e] = cv.u;
            }

        // --- PV: O[16 q][128 d] += P[16][64] @ V[64][128] ---
        __builtin_amdgcn_s_setprio(1);
#pragma unroll
        for (int c = 0; c < 2; ++c)
#pragma unroll
            for (int f = 0; f < 8; ++f) {
                int phys = (c * 4 + lg) ^ (l16 & 7);
                ushort8_t vf = *(const ushort8_t*)&Vt[vbuf][l16 + 16 * f][phys * 8];
                o[f] = __builtin_amdgcn_mfma_f32_16x16x32_bf16(as_bf(paf[c]), as_bf(vf), o[f], 0, 0, 0);
            }
        __builtin_amdgcn_s_setprio(0);
        // no bottom barrier: next top barrier orders PV reads vs next V staging
    }

    // --- epilogue: normalize (redistribute 1/lstate to o's q-rows) and store ---
    float li = 1.0f / lstate;
    float linv[4];
#pragma unroll
    for (int r = 0; r < 4; ++r) linv[r] = __shfl(li, 4 * lg + r);
#pragma unroll
    for (int f = 0; f < 8; ++f)
#pragma unroll
        for (int r = 0; r < 4; ++r) {
            int q_g = qb0 + lg * 4 + r;
            size_t row = (size_t)(q_g * BATCH + b_idx) * HIDDEN;
            attn_out[row + h * HD + 16 * f + l16] = f2bf(o[f][r] * linv[r]);
        }
}

extern "C" void kernel_launch(void* const* d_in, const int* in_sizes, int n_in,
                              void* d_out, int out_size, void* d_ws, size_t ws_size,
                              hipStream_t stream) {
    const float* x     = (const float*)d_in[0];
    const float* wqkv  = (const float*)d_in[1];
    const float* wproj = (const float*)d_in[2];
    float* out = (float*)d_out;

    unsigned short* qkv   = (unsigned short*)d_ws;                    // [NTOK][TPROJ]
    unsigned short* attn  = qkv  + (size_t)NTOK * TPROJ;              // [NTOK][HIDDEN]
    unsigned short* vT    = attn + (size_t)NTOK * HIDDEN;             // [B*NKV*HD][SEQ]
    unsigned short* xb    = vT   + (size_t)BATCH * NKV * HD * SEQ;    // [NTOK][HIDDEN]
    unsigned short* wqkvb = xb   + (size_t)NTOK * HIDDEN;             // [TPROJ][HIDDEN]
    unsigned short* wprojb= wqkvb+ (size_t)TPROJ * HIDDEN;            // [HIDDEN][HIDDEN]

    // 0) fused bf16 pre-convert
    conv3_kernel<<<dim3((unsigned)((CONV_N0 + CONV_N1 + CONV_N2) / 2048)), 256, 0, stream>>>(
        x, wqkv, wproj, xb, wqkvb, wprojb);

    // 1) QKV projection: qkv = x @ wqkv^T  (bf16 in, bf16 out). 192 blocks
    gemm256_kernel<true><<<dim3((NTOK / 256) * (TPROJ / 256)), 512, 0, stream>>>(
        xb, wqkvb, (void*)qkv, NTOK, TPROJ, HIDDEN);

    // 2) V pre-transpose
    vtrans_kernel<<<dim3(SEQ / 128, BATCH * NKV), 256, 0, stream>>>(qkv, vT);

    // 3) causal GQA flash attention (1024 blocks, longest-first)
    attn_kernel<<<dim3(1024), 256, 0, stream>>>(qkv, vT, attn);

    // 4) output projection: 128x128 tile -> 512 blocks = 2 blocks/CU
    gemm_proj_kernel<<<dim3((NTOK / 128) * (HIDDEN / 128)), 256, 0, stream>>>(
        attn, wprojb, out, NTOK, HIDDEN, HIDDEN);
}

// Round 17
// 178.303 us; speedup vs baseline: 1.0652x; 1.0193x over previous
//
#include <hip/hip_runtime.h>

#define SEQ 2048
#define BATCH 2
#define HIDDEN 2048
#define NHEADS 16
#define NKV 4
#define HD 128
#define GROUP 768       // (4+2)*128
#define TPROJ 3072      // 4*768
#define NTOK (SEQ*BATCH)  // 4096

typedef __attribute__((ext_vector_type(8))) __bf16 bf16x8;
typedef __attribute__((ext_vector_type(8))) unsigned short ushort8_t;
typedef __attribute__((ext_vector_type(4))) float f32x4;

union U8cast { ushort8_t u; bf16x8 b; };
__device__ inline bf16x8 as_bf(ushort8_t u) { U8cast c; c.u = u; return c.b; }

union Bf16U { __bf16 h; unsigned short u; };

// fp32 -> bf16 round-to-nearest-even
__device__ inline unsigned short f2bf(float f) {
    unsigned int u = __float_as_uint(f);
    return (unsigned short)((u + 0x7FFFu + ((u >> 16) & 1u)) >> 16);
}

__device__ inline ushort8_t load8_f32_bf16(const float* __restrict__ p) {
    float4 v0 = *(const float4*)p;
    float4 v1 = *(const float4*)(p + 4);
    ushort8_t u;
    u[0] = f2bf(v0.x); u[1] = f2bf(v0.y); u[2] = f2bf(v0.z); u[3] = f2bf(v0.w);
    u[4] = f2bf(v1.x); u[5] = f2bf(v1.y); u[6] = f2bf(v1.z); u[7] = f2bf(v1.w);
    return u;
}

// native 2^x
__device__ inline float exp2a(float x) {
    float r; asm("v_exp_f32 %0, %1" : "=v"(r) : "v"(x)); return r;
}

// async global->LDS DMA, 16B per lane. LDS dest = wave-uniform base + lane*16.
__device__ inline void gload_lds16(const unsigned short* g, unsigned short* l) {
    __builtin_amdgcn_global_load_lds(
        (const __attribute__((address_space(1))) void*)g,
        (__attribute__((address_space(3))) void*)l, 16, 0, 0);
}

#define CONV_N0 ((size_t)NTOK * HIDDEN)    // x:      8388608
#define CONV_N1 ((size_t)TPROJ * HIDDEN)   // wqkv:   6291456
#define CONV_N2 ((size_t)HIDDEN * HIDDEN)  // wproj:  4194304

// fp32 -> bf16 convert of x + wqkv (only what the QKV GEMM needs; wproj is
// converted by the idle-CU blocks of the fused QKV launch below)
__global__ __launch_bounds__(256) void conv2_kernel(
    const float* __restrict__ x, const float* __restrict__ wq,
    unsigned short* __restrict__ xb, unsigned short* __restrict__ wqb)
{
    size_t i = (size_t)(blockIdx.x * 256 + threadIdx.x) * 8;
    if (i < CONV_N0) {
        *(ushort8_t*)(xb + i) = load8_f32_bf16(x + i);
    } else {
        size_t j = i - CONV_N0;
        *(ushort8_t*)(wqb + j) = load8_f32_bf16(wq + j);
    }
}

// ===========================================================================
// FUSED QKV GEMM + wproj conversion. Grid 256 x 512thr:
//   blocks 0..191  : 256x256 coarse counted-vmcnt GEMM (R8/R9 config,
//                    session-best; 128 KB LDS, 1 block/CU)
//   blocks 192..255: grid-stride wproj fp32->bf16 conversion — runs on the
//                    64 CUs the 192-block GEMM leaves idle (independent data;
//                    consumed only by the later proj GEMM launch).
// ===========================================================================
__global__ __launch_bounds__(512, 2) void gemm_qkv_fused_kernel(
    const unsigned short* __restrict__ A, const unsigned short* __restrict__ B,
    unsigned short* __restrict__ C,
    const float* __restrict__ wp, unsigned short* __restrict__ wpb,
    int M, int N, int K)
{
    __shared__ unsigned short lds[2][2][256 * 64];   // [buf][0=A,1=B], 128 KiB

    const int bid = (int)blockIdx.x;
    if (bid >= 192) {
        // ---- converter role: wproj fp32 -> bf16, 64 blocks x 512 thr ----
        const size_t stride = (size_t)64 * 512 * 8;
        size_t i = ((size_t)(bid - 192) * 512 + threadIdx.x) * 8;
        for (; i < CONV_N2; i += stride)
            *(ushort8_t*)(wpb + i) = load8_f32_bf16(wp + i);
        return;
    }

    const int t = threadIdx.x, lane = t & 63, w = t >> 6;
    const int wm = w >> 2, wn = w & 3;
    const int l16 = lane & 15, lg = lane >> 4;

    // bijective XCD swizzle over the 192 GEMM blocks (192 % 8 == 0)
    const int cpx = 24;
    const int wg  = (bid & 7) * cpx + (bid >> 3);
    const int nbn = N >> 8;
    const int m0 = (wg / nbn) << 8, n0 = (wg % nbn) << 8;
    const int NKT = K >> 6;

    const int srow = lane >> 3;
    const int scol = ((lane & 7) ^ srow) << 3;

    f32x4 acc[8][4] = {};

    auto stage = [&](const unsigned short* __restrict__ G, int g0, int kt, int op) {
        const int k0 = kt << 6;
        unsigned short* Ld = lds[kt & 1][op];
#pragma unroll
        for (int i = 0; i < 4; ++i) {
            const int r = w * 32 + i * 8;
            gload_lds16(G + (size_t)(g0 + r + srow) * K + k0 + scol, Ld + r * 64);
        }
    };

    stage(A, m0, 0, 0); stage(B, n0, 0, 1);
    stage(A, m0, 1, 0); stage(B, n0, 1, 1);

    for (int kt = 0; kt < NKT; ++kt) {
        const unsigned short* As_ = lds[kt & 1][0];
        const unsigned short* Bs_ = lds[kt & 1][1];

        if (kt < NKT - 1) asm volatile("s_waitcnt vmcnt(8)" ::: "memory");
        else              asm volatile("s_waitcnt vmcnt(0)" ::: "memory");
        __builtin_amdgcn_sched_barrier(0);
        __builtin_amdgcn_s_barrier();
        __builtin_amdgcn_sched_barrier(0);

        bf16x8 aR[8], b0R[4], b1R[4];

#pragma unroll
        for (int i = 0; i < 4; ++i)
#pragma unroll
            for (int s = 0; s < 2; ++s) {
                int row  = wm * 128 + i * 16 + l16;
                int slot = ((s << 2) | lg) ^ (l16 & 7);
                aR[i * 2 + s] = as_bf(*(const ushort8_t*)&As_[row * 64 + slot * 8]);
            }
#pragma unroll
        for (int j = 0; j < 2; ++j)
#pragma unroll
            for (int s = 0; s < 2; ++s) {
                int row  = wn * 64 + j * 16 + l16;
                int slot = ((s << 2) | lg) ^ (l16 & 7);
                b0R[j * 2 + s] = as_bf(*(const ushort8_t*)&Bs_[row * 64 + slot * 8]);
            }
        __builtin_amdgcn_s_setprio(1);
#pragma unroll
        for (int i = 0; i < 4; ++i)
#pragma unroll
            for (int j = 0; j < 2; ++j)
#pragma unroll
                for (int s = 0; s < 2; ++s)
                    acc[i][j] = __builtin_amdgcn_mfma_f32_16x16x32_bf16(aR[i*2+s], b0R[j*2+s], acc[i][j], 0, 0, 0);
        __builtin_amdgcn_s_setprio(0);

#pragma unroll
        for (int j = 0; j < 2; ++j)
#pragma unroll
            for (int s = 0; s < 2; ++s) {
                int row  = wn * 64 + 32 + j * 16 + l16;
                int slot = ((s << 2) | lg) ^ (l16 & 7);
                b1R[j * 2 + s] = as_bf(*(const ushort8_t*)&Bs_[row * 64 + slot * 8]);
            }
        __builtin_amdgcn_s_setprio(1);
#pragma unroll
        for (int i = 0; i < 4; ++i)
#pragma unroll
            for (int j = 0; j < 2; ++j)
#pragma unroll
                for (int s = 0; s < 2; ++s)
                    acc[i][2 + j] = __builtin_amdgcn_mfma_f32_16x16x32_bf16(aR[i*2+s], b1R[j*2+s], acc[i][2 + j], 0, 0, 0);
        __builtin_amdgcn_s_setprio(0);

        __builtin_amdgcn_sched_barrier(0);
        __builtin_amdgcn_s_barrier();
        __builtin_amdgcn_sched_barrier(0);
        if (kt + 2 < NKT) stage(B, n0, kt + 2, 1);
        __builtin_amdgcn_sched_barrier(0);

#pragma unroll
        for (int i = 0; i < 4; ++i)
#pragma unroll
            for (int s = 0; s < 2; ++s) {
                int row  = wm * 128 + 64 + i * 16 + l16;
                int slot = ((s << 2) | lg) ^ (l16 & 7);
                aR[i * 2 + s] = as_bf(*(const ushort8_t*)&As_[row * 64 + slot * 8]);
            }
        __builtin_amdgcn_s_setprio(1);
#pragma unroll
        for (int i = 0; i < 4; ++i)
#pragma unroll
            for (int j = 0; j < 2; ++j)
#pragma unroll
                for (int s = 0; s < 2; ++s)
                    acc[4 + i][2 + j] = __builtin_amdgcn_mfma_f32_16x16x32_bf16(aR[i*2+s], b1R[j*2+s], acc[4 + i][2 + j], 0, 0, 0);
        __builtin_amdgcn_s_setprio(0);

        __builtin_amdgcn_sched_barrier(0);
        __builtin_amdgcn_s_barrier();
        __builtin_amdgcn_sched_barrier(0);
        if (kt + 2 < NKT) stage(A, m0, kt + 2, 0);
        __builtin_amdgcn_sched_barrier(0);

        __builtin_amdgcn_s_setprio(1);
#pragma unroll
        for (int i = 0; i < 4; ++i)
#pragma unroll
            for (int j = 0; j < 2; ++j)
#pragma unroll
                for (int s = 0; s < 2; ++s)
                    acc[4 + i][j] = __builtin_amdgcn_mfma_f32_16x16x32_bf16(aR[i*2+s], b0R[j*2+s], acc[4 + i][j], 0, 0, 0);
        __builtin_amdgcn_s_setprio(0);
    }

#pragma unroll
    for (int ia = 0; ia < 8; ++ia)
#pragma unroll
        for (int jb = 0; jb < 4; ++jb)
#pragma unroll
            for (int r = 0; r < 4; ++r) {
                int row = m0 + wm * 128 + (ia >> 2) * 64 + (ia & 3) * 16 + lg * 4 + r;
                int col = n0 + wn * 64 + (jb >> 1) * 32 + (jb & 1) * 16 + l16;
                C[(size_t)row * N + col] = f2bf(acc[ia][jb][r]);
            }
}

// ===========================================================================
// Output projection GEMM (R16 winner): 128x128 tile, 256 thr (4 waves 2Mx2N),
// BK=64, dbuf LDS = 64 KB -> 2 BLOCKS/CU (grid 512). Two independent barrier
// domains per CU hide each other's vmcnt/barrier stalls.
// ===========================================================================
__global__ __launch_bounds__(256, 2) void gemm_proj_kernel(
    const unsigned short* __restrict__ A, const unsigned short* __restrict__ B,
    float* __restrict__ C, int M, int N, int K)
{
    __shared__ unsigned short ldsA[2][128 * 64];   // 32 KiB
    __shared__ unsigned short ldsB[2][128 * 64];   // 32 KiB

    const int t = threadIdx.x, lane = t & 63, w = t >> 6;
    const int wm = w >> 1, wn = w & 1;
    const int l16 = lane & 15, lg = lane >> 4;

    const int cpx = (int)gridDim.x >> 3;
    const int wg  = ((int)blockIdx.x & 7) * cpx + ((int)blockIdx.x >> 3);
    const int nbn = N >> 7;
    const int m0 = (wg / nbn) << 7, n0 = (wg % nbn) << 7;
    const int NKT = K >> 6;

    const int srow = lane >> 3;
    const int scol = ((lane & 7) ^ srow) << 3;

    f32x4 acc[4][4] = {};

    auto stageA = [&](int kt) {
        const int k0 = kt << 6;
        unsigned short* Ld = ldsA[kt & 1];
#pragma unroll
        for (int i = 0; i < 4; ++i) {
            const int r = w * 32 + i * 8;
            gload_lds16(A + (size_t)(m0 + r + srow) * K + k0 + scol, Ld + r * 64);
        }
    };
    auto stageB = [&](int kt) {
        const int k0 = kt << 6;
        unsigned short* Ld = ldsB[kt & 1];
#pragma unroll
        for (int i = 0; i < 4; ++i) {
            const int r = w * 32 + i * 8;
            gload_lds16(B + (size_t)(n0 + r + srow) * K + k0 + scol, Ld + r * 64);
        }
    };

    stageA(0); stageB(0);
    stageA(1); stageB(1);

    for (int kt = 0; kt < NKT; ++kt) {
        const unsigned short* As_ = ldsA[kt & 1];
        const unsigned short* Bs_ = ldsB[kt & 1];

        if (kt < NKT - 1) asm volatile("s_waitcnt vmcnt(8)" ::: "memory");
        else              asm volatile("s_waitcnt vmcnt(0)" ::: "memory");
        __builtin_amdgcn_sched_barrier(0);
        __builtin_amdgcn_s_barrier();
        __builtin_amdgcn_sched_barrier(0);

        bf16x8 aR[4], b0R[4], b1R[4];

#pragma unroll
        for (int i = 0; i < 2; ++i)
#pragma unroll
            for (int s = 0; s < 2; ++s) {
                int row  = wm * 64 + i * 16 + l16;
                int slot = ((s << 2) | lg) ^ (l16 & 7);
                aR[i * 2 + s] = as_bf(*(const ushort8_t*)&As_[row * 64 + slot * 8]);
            }
#pragma unroll
        for (int j = 0; j < 2; ++j)
#pragma unroll
            for (int s = 0; s < 2; ++s) {
                int row  = wn * 64 + j * 16 + l16;
                int slot = ((s << 2) | lg) ^ (l16 & 7);
                b0R[j * 2 + s] = as_bf(*(const ushort8_t*)&Bs_[row * 64 + slot * 8]);
            }
        __builtin_amdgcn_s_setprio(1);
#pragma unroll
        for (int i = 0; i < 2; ++i)
#pragma unroll
            for (int j = 0; j < 2; ++j)
#pragma unroll
                for (int s = 0; s < 2; ++s)
                    acc[i][j] = __builtin_amdgcn_mfma_f32_16x16x32_bf16(aR[i*2+s], b0R[j*2+s], acc[i][j], 0, 0, 0);
        __builtin_amdgcn_s_setprio(0);

#pragma unroll
        for (int j = 0; j < 2; ++j)
#pragma unroll
            for (int s = 0; s < 2; ++s) {
                int row  = wn * 64 + 32 + j * 16 + l16;
                int slot = ((s << 2) | lg) ^ (l16 & 7);
                b1R[j * 2 + s] = as_bf(*(const ushort8_t*)&Bs_[row * 64 + slot * 8]);
            }
        __builtin_amdgcn_s_setprio(1);
#pragma unroll
        for (int i = 0; i < 2; ++i)
#pragma unroll
            for (int j = 0; j < 2; ++j)
#pragma unroll
                for (int s = 0; s < 2; ++s)
                    acc[i][2 + j] = __builtin_amdgcn_mfma_f32_16x16x32_bf16(aR[i*2+s], b1R[j*2+s], acc[i][2 + j], 0, 0, 0);
        __builtin_amdgcn_s_setprio(0);

        __builtin_amdgcn_sched_barrier(0);
        __builtin_amdgcn_s_barrier();
        __builtin_amdgcn_sched_barrier(0);
        if (kt + 2 < NKT) stageB(kt + 2);
        __builtin_amdgcn_sched_barrier(0);

#pragma unroll
        for (int i = 0; i < 2; ++i)
#pragma unroll
            for (int s = 0; s < 2; ++s) {
                int row  = wm * 64 + 32 + i * 16 + l16;
                int slot = ((s << 2) | lg) ^ (l16 & 7);
                aR[i * 2 + s] = as_bf(*(const ushort8_t*)&As_[row * 64 + slot * 8]);
            }
        __builtin_amdgcn_s_setprio(1);
#pragma unroll
        for (int i = 0; i < 2; ++i)
#pragma unroll
            for (int j = 0; j < 2; ++j)
#pragma unroll
                for (int s = 0; s < 2; ++s)
                    acc[2 + i][2 + j] = __builtin_amdgcn_mfma_f32_16x16x32_bf16(aR[i*2+s], b1R[j*2+s], acc[2 + i][2 + j], 0, 0, 0);
        __builtin_amdgcn_s_setprio(0);

        __builtin_amdgcn_sched_barrier(0);
        __builtin_amdgcn_s_barrier();
        __builtin_amdgcn_sched_barrier(0);
        if (kt + 2 < NKT) stageA(kt + 2);
        __builtin_amdgcn_sched_barrier(0);

        __builtin_amdgcn_s_setprio(1);
#pragma unroll
        for (int i = 0; i < 2; ++i)
#pragma unroll
            for (int j = 0; j < 2; ++j)
#pragma unroll
                for (int s = 0; s < 2; ++s)
                    acc[2 + i][j] = __builtin_amdgcn_mfma_f32_16x16x32_bf16(aR[i*2+s], b0R[j*2+s], acc[2 + i][j], 0, 0, 0);
        __builtin_amdgcn_s_setprio(0);
    }

#pragma unroll
    for (int i = 0; i < 4; ++i)
#pragma unroll
        for (int j = 0; j < 4; ++j)
#pragma unroll
            for (int r = 0; r < 4; ++r) {
                int row = m0 + wm * 64 + i * 16 + lg * 4 + r;
                int col = n0 + wn * 64 + j * 16 + l16;
                C[(size_t)row * N + col] = acc[i][j][r];
            }
}

// V pre-transpose: vT[(bk*HD + d)*SEQ + s] = V[s,b,kvh][d], bk = b*NKV+kvh.
__global__ __launch_bounds__(256) void vtrans_kernel(const unsigned short* __restrict__ qkv,
                                                     unsigned short* __restrict__ vT)
{
    const int t = threadIdx.x;
    const int s0 = blockIdx.x * 128 + (t & 15) * 8;
    const int bk = blockIdx.y;
    const int b_idx = bk >> 2;
    const int voff = (bk & 3) * GROUP + 640;
    const int d0 = (t >> 4) * 8;
    ushort8_t in[8];
#pragma unroll
    for (int j = 0; j < 8; ++j)
        in[j] = *(const ushort8_t*)(qkv + (size_t)((s0 + j) * BATCH + b_idx) * TPROJ + voff + d0);
#pragma unroll
    for (int dd = 0; dd < 8; ++dd) {
        ushort8_t ov;
#pragma unroll
        for (int j = 0; j < 8; ++j) ov[j] = in[j][dd];
        *(ushort8_t*)(vT + (size_t)(bk * HD + d0 + dd) * SEQ + s0) = ov;
    }
}

// ===========================================================================
// Flash attention (EXACT R9/R16 session-best config, measured ~66.5 us):
// swapped QK^T + kv-permuted K; K single-buf + V double-buf (48 KB). FROZEN.
// ===========================================================================
__global__ __launch_bounds__(256, 4) void attn_kernel(const unsigned short* __restrict__ qkv,
                                                      const unsigned short* __restrict__ vT,
                                                      unsigned short* __restrict__ attn_out)
{
    __shared__ unsigned short Ks[64][128];           // K  [kv-logical][d], slot-swizzled
    __shared__ unsigned short Vt[2][128][64];        // V^T[d][kv], slot-swizzled, dbuf

    const int t = threadIdx.x, lane = t & 63, w = t >> 6;
    const int l16 = lane & 15, lg = lane >> 4;

    // longest-first dispatch
    const int bid = (int)blockIdx.x;
    const int qt  = 127 - (bid >> 3);          // q-tile (16 rows)
    const int bk  = bid & 7;
    const int b_idx = bk >> 2;
    const int kvh   = bk & 3;
    const int qb0   = qt * 16;
    const int qoff  = kvh * GROUP + w * HD;    // this wave's q-head
    const int koff  = kvh * GROUP + 512;
    const int vrow0 = (b_idx * NKV + kvh) * HD;
    const int h     = kvh * 4 + w;

    const float SCL2 = 0.08838834764831845f * 1.44269504f;  // scale*log2(e)
    const float THRU = 8.0f / SCL2;                          // defer-max threshold

    // Q as B-operand fragments: row = l16 = q, k-chunk by lg
    ushort8_t qf[4];
    {
        size_t qrow = (size_t)((qb0 + l16) * BATCH + b_idx) * TPROJ + qoff;
#pragma unroll
        for (int kc = 0; kc < 4; ++kc)
            qf[kc] = *(const ushort8_t*)(qkv + qrow + kc * 32 + lg * 8);
    }

    f32x4 o[8] = {};                       // O: q = qb0 + 4*lg + r, d = 16f + l16
    float mstate = -1e30f, lstate = 0.f, negm2 = 0.f;   // per-lane, q = qb0 + l16

    const int nIter = (qt >> 2) + 1;       // KV tiles of 64 (causal)

    // DMA stage: pre-swizzled global source, linear LDS dest (rule #21).
    auto stageK = [&](int it) {
        const int kv0 = it << 6;
#pragma unroll
        for (int i = 0; i < 4; ++i) {
            int rl = w * 16 + i * 4 + (lane >> 4);          // lds logical row
            int pr = 32 * ((rl >> 4) & 1) + 8 * ((rl >> 2) & 3) + 4 * (rl >> 5) + (rl & 3);
            int g  = (lane & 15) ^ (rl & 7);                // source slot
            gload_lds16(qkv + (size_t)((kv0 + pr) * BATCH + b_idx) * TPROJ + koff + g * 8,
                        &Ks[w * 16 + i * 4][0]);
        }
    };
    auto stageV = [&](int it) {
        const int kv0 = it << 6;
        const int buf = it & 1;
#pragma unroll
        for (int i = 0; i < 4; ++i) {
            int rl = w * 32 + i * 8 + (lane >> 3);
            int g  = (lane & 7) ^ ((lane >> 3) & 7);
            gload_lds16(vT + (size_t)(vrow0 + rl) * SEQ + kv0 + g * 8,
                        &Vt[buf][w * 32 + i * 8][0]);
        }
    };

    stageK(0); stageV(0);

    for (int it = 0; it < nIter; ++it) {
        const int kv0 = it * 64;
        const int vbuf = it & 1;

        asm volatile("s_waitcnt vmcnt(0)" ::: "memory");  // all covered >= a phase ago
        __builtin_amdgcn_sched_barrier(0);
        __builtin_amdgcn_s_barrier();        // tile it visible to all waves
        __builtin_amdgcn_sched_barrier(0);

        // V(it+1) into the other buffer (its readers retired before the barrier)
        if (it + 1 < nIter) stageV(it + 1);
        __builtin_amdgcn_sched_barrier(0);

        // --- swapped QK^T: s[nf] = K_frag(nf) . Q^T -> D[kv-local][q=l16] ---
        f32x4 s[4] = {};
        __builtin_amdgcn_s_setprio(1);
#pragma unroll
        for (int nf = 0; nf < 4; ++nf)
#pragma unroll
            for (int kc = 0; kc < 4; ++kc) {
                int phys = (kc * 4 + lg) ^ (l16 & 7);
                ushort8_t kb = *(const ushort8_t*)&Ks[nf * 16 + l16][phys * 8];
                s[nf] = __builtin_amdgcn_mfma_f32_16x16x32_bf16(as_bf(kb), as_bf(qf[kc]), s[nf], 0, 0, 0);
            }
        __builtin_amdgcn_s_setprio(0);

        // K reads retired -> barrier, then restage K (hides under softmax+PV)
        __builtin_amdgcn_sched_barrier(0);
        __builtin_amdgcn_s_barrier();
        __builtin_amdgcn_sched_barrier(0);
        if (it + 1 < nIter) stageK(it + 1);
        __builtin_amdgcn_sched_barrier(0);

        // --- causal mask (final tile only); value (nf,r) is PHYSICAL kv:
        //     kv0 + 32*(nf&1) + 8*lg + 4*(nf>>1) + r ---
        if (it == nIter - 1) {
            const int q_g = qb0 + l16;
#pragma unroll
            for (int nf = 0; nf < 4; ++nf)
#pragma unroll
                for (int r = 0; r < 4; ++r) {
                    int kv_g = kv0 + 32 * (nf & 1) + 8 * lg + 4 * (nf >> 1) + r;
                    if (kv_g > q_g) s[nf][r] = -1e30f;
                }
        }

        // --- row max: in-lane tree + 2 shfl rounds over lane replicas ---
        float a0 = fmaxf(fmaxf(s[0][0], s[0][1]), fmaxf(s[0][2], s[0][3]));
        float a1 = fmaxf(fmaxf(s[1][0], s[1][1]), fmaxf(s[1][2], s[1][3]));
        float a2 = fmaxf(fmaxf(s[2][0], s[2][1]), fmaxf(s[2][2], s[2][3]));
        float a3 = fmaxf(fmaxf(s[3][0], s[3][1]), fmaxf(s[3][2], s[3][3]));
        float rmax = fmaxf(fmaxf(a0, a1), fmaxf(a2, a3));
        rmax = fmaxf(rmax, __shfl_xor(rmax, 16));
        rmax = fmaxf(rmax, __shfl_xor(rmax, 32));

        // --- defer-max: rescale only when max grew beyond threshold ---
        if (!__all(rmax - mstate <= THRU)) {
            float mn = fmaxf(mstate, rmax);
            float corr = exp2a((mstate - mn) * SCL2);
            mstate = mn;
            negm2  = -mn * SCL2;
            lstate *= corr;
            float co[4];
#pragma unroll
            for (int r = 0; r < 4; ++r) co[r] = __shfl(corr, 4 * lg + r);
#pragma unroll
            for (int f = 0; f < 8; ++f)
#pragma unroll
                for (int r = 0; r < 4; ++r) o[f][r] *= co[r];
        }

        // --- P = exp2(s*SCL2 - m*SCL2) in place; in-lane row sum ---
        float rs0 = 0.f, rs1 = 0.f;
#pragma unroll
        for (int nf = 0; nf < 4; ++nf)
#pragma unroll
            for (int r = 0; r < 4; ++r) {
                float pv = exp2a(fmaf(s[nf][r], SCL2, negm2));
                s[nf][r] = pv;
                if (nf < 2) rs0 += pv; else rs1 += pv;
            }
        float rsum = rs0 + rs1;
        rsum += __shfl_xor(rsum, 16);
        rsum += __shfl_xor(rsum, 32);
        lstate += rsum;

        // paf[c]: elems 0..3 = p[c][0..3], elems 4..7 = p[2+c][0..3]
        ushort8_t paf[2];
#pragma unroll
        for (int c = 0; c < 2; ++c)
#pragma unroll
            for (int e = 0; e < 8; ++e) {
                Bf16U cv; cv.h = (__bf16)((e < 4) ? s[c][e] : s[2 + c][e - 4]);
                paf[c][e] = cv.u;
            }

        // --- PV: O[16 q][128 d] += P[16][64] @ V[64][128] ---
        __builtin_amdgcn_s_setprio(1);
#pragma unroll
        for (int c = 0; c < 2; ++c)
#pragma unroll
            for (int f = 0; f < 8; ++f) {
                int phys = (c * 4 + lg) ^ (l16 & 7);
                ushort8_t vf = *(const ushort8_t*)&Vt[vbuf][l16 + 16 * f][phys * 8];
                o[f] = __builtin_amdgcn_mfma_f32_16x16x32_bf16(as_bf(paf[c]), as_bf(vf), o[f], 0, 0, 0);
            }
        __builtin_amdgcn_s_setprio(0);
        // no bottom barrier: next top barrier orders PV reads vs next V staging
    }

    // --- epilogue: normalize (redistribute 1/lstate to o's q-rows) and store ---
    float li = 1.0f / lstate;
    float linv[4];
#pragma unroll
    for (int r = 0; r < 4; ++r) linv[r] = __shfl(li, 4 * lg + r);
#pragma unroll
    for (int f = 0; f < 8; ++f)
#pragma unroll
        for (int r = 0; r < 4; ++r) {
            int q_g = qb0 + lg * 4 + r;
            size_t row = (size_t)(q_g * BATCH + b_idx) * HIDDEN;
            attn_out[row + h * HD + 16 * f + l16] = f2bf(o[f][r] * linv[r]);
        }
}

extern "C" void kernel_launch(void* const* d_in, const int* in_sizes, int n_in,
                              void* d_out, int out_size, void* d_ws, size_t ws_size,
                              hipStream_t stream) {
    const float* x     = (const float*)d_in[0];
    const float* wqkv  = (const float*)d_in[1];
    const float* wproj = (const float*)d_in[2];
    float* out = (float*)d_out;

    unsigned short* qkv   = (unsigned short*)d_ws;                    // [NTOK][TPROJ]
    unsigned short* attn  = qkv  + (size_t)NTOK * TPROJ;              // [NTOK][HIDDEN]
    unsigned short* vT    = attn + (size_t)NTOK * HIDDEN;             // [B*NKV*HD][SEQ]
    unsigned short* xb    = vT   + (size_t)BATCH * NKV * HD * SEQ;    // [NTOK][HIDDEN]
    unsigned short* wqkvb = xb   + (size_t)NTOK * HIDDEN;             // [TPROJ][HIDDEN]
    unsigned short* wprojb= wqkvb+ (size_t)TPROJ * HIDDEN;            // [HIDDEN][HIDDEN]

    // 0) bf16 pre-convert of x + wqkv only (wproj converts inside launch 1)
    conv2_kernel<<<dim3((unsigned)((CONV_N0 + CONV_N1) / 2048)), 256, 0, stream>>>(
        x, wqkv, xb, wqkvb);

    // 1) FUSED: QKV projection (192 GEMM blocks) + wproj conversion on the
    //    64 otherwise-idle CUs. Grid 256 x 512 threads.
    gemm_qkv_fused_kernel<<<dim3(256), 512, 0, stream>>>(
        xb, wqkvb, qkv, wproj, wprojb, NTOK, TPROJ, HIDDEN);

    // 2) V pre-transpose
    vtrans_kernel<<<dim3(SEQ / 128, BATCH * NKV), 256, 0, stream>>>(qkv, vT);

    // 3) causal GQA flash attention (1024 blocks, longest-first)
    attn_kernel<<<dim3(1024), 256, 0, stream>>>(qkv, vT, attn);

    // 4) output projection: 128x128 tile -> 512 blocks = 2 blocks/CU
    gemm_proj_kernel<<<dim3((NTOK / 128) * (HIDDEN / 128)), 256, 0, stream>>>(
        attn, wprojb, out, NTOK, HIDDEN, HIDDEN);
}